// Round 8
// baseline (126.959 us; speedup 1.0000x reference)
//
#include <hip/hip_runtime.h>

// alpha = log2(e)/sqrt(8); Q pre-scaled by sqrt(alpha) so score = exp2(q'.q')
#define SQRT_ALPHA     0.71419163f
#define INV_SQRT_ALPHA 1.40018452f

__device__ __forceinline__ float2 pk_fma(float2 a, float2 b, float2 c) {
    return make_float2(fmaf(a.x, b.x, c.x), fmaf(a.y, b.y, c.y));
}

// analytic circuit: exp[0]=prod_{1..7}cos(x_w+th_w); exp[k]=prod_{0..k}cos(...)
__device__ __forceinline__ void build_qrow(const float* __restrict__ xp,
                                           const float* th, float* q) {
    float4 xa = *reinterpret_cast<const float4*>(xp);
    float4 xb = *reinterpret_cast<const float4*>(xp + 4);
    float c[8];
    c[0] = __cosf(xa.x + th[0]); c[1] = __cosf(xa.y + th[1]);
    c[2] = __cosf(xa.z + th[2]); c[3] = __cosf(xa.w + th[3]);
    c[4] = __cosf(xb.x + th[4]); c[5] = __cosf(xb.y + th[5]);
    c[6] = __cosf(xb.z + th[6]); c[7] = __cosf(xb.w + th[7]);
    float pre = c[0];
    #pragma unroll
    for (int k = 1; k < 8; k++) { pre *= c[k]; q[k] = pre * SQRT_ALPHA; }
    float suf = 1.f;
    #pragma unroll
    for (int w = 7; w >= 1; w--) suf *= c[w];
    q[0] = suf * SQRT_ALPHA;
}

// ONE dispatch, no workspace, no atomics, no cross-block sync, ONE barrier.
// grid (8 b, 32 chunks of 16 tokens), block 512 = 8 waves; wave wv = head wv.
// Each wave: builds its head's 512 K-rows into registers (8 rows/lane),
// stages them via wave-private double-buffered LDS tiles (wave-synchronous,
// no barrier), runs flash attention for the chunk's 16 rows (4 rows/lane x
// 16 j-slices; no max-sub: |score'|<=4.08), in-wave butterfly reduce, stash
// ctx in LDS. One __syncthreads, then proj: out = ctx.Wo^T + bo.
// grid.x = b -> XCD = b: each XCD's 32 blocks share one 1MB x-slab in L2.
__global__ __launch_bounds__(512) void fused_heads_kernel(
    const float* __restrict__ x,      // fp32 [8,512,64]
    const float* __restrict__ theta,  // fp32 [8]
    const float* __restrict__ Wo,     // fp32 [64][64]
    const float* __restrict__ bo,     // fp32 [64]
    float* __restrict__ out)          // fp32 [4096][64]
{
    __shared__ float tile[8][2][64][10]; // 40 KB wave-private dbuf, pitch 10
    __shared__ float ctxL[16][68];       // 4.4 KB ctx rows (16B-aligned pitch)

    const int b     = blockIdx.x;     // 0..7
    const int chunk = blockIdx.y;     // 0..31 -> tokens [16*chunk, +16)
    const int tid  = threadIdx.x;
    const int lane = tid & 63;
    const int wv   = tid >> 6;        // 0..7 == head h
    const int h    = wv;

    float th[8];
    #pragma unroll
    for (int w = 0; w < 8; w++) th[w] = theta[w];

    const float* xb = x + (size_t)b * 512 * 64 + h * 8;

    // ---- K-rows of this head: lane owns rows (64t + lane), t = 0..7 ----
    float u[8][8];
    #pragma unroll
    for (int t = 0; t < 8; t++)
        build_qrow(xb + (size_t)(t * 64 + lane) * 64, th, u[t]);

    // ---- Q-rows: lane handles rows chunk*16 + 4g + k, g = lane&3 ----
    const int g  = lane & 3;          // row group
    const int js = lane >> 2;         // j-slice 0..15 (32 j each, strided)
    float2 q01[4], q23[4], q45[4], q67[4];
    #pragma unroll
    for (int k = 0; k < 4; k++) {
        float q[8];
        build_qrow(xb + (size_t)(chunk * 16 + 4 * g + k) * 64, th, q);
        q01[k] = make_float2(q[0], q[1]); q23[k] = make_float2(q[2], q[3]);
        q45[k] = make_float2(q[4], q[5]); q67[k] = make_float2(q[6], q[7]);
    }

    float2 a01[4], a23[4], a45[4], a67[4];
    float l[4];
    #pragma unroll
    for (int k = 0; k < 4; k++) {
        a01[k] = make_float2(0.f, 0.f); a23[k] = a01[k];
        a45[k] = a01[k]; a67[k] = a01[k]; l[k] = 0.f;
    }

    // ---- 8 tiles of 64 j; wave-synchronous staging (no __syncthreads) ----
    #pragma unroll
    for (int t = 0; t < 8; t++) {
        float* wp = &tile[wv][t & 1][lane][0];
        *reinterpret_cast<float2*>(wp + 0) = make_float2(u[t][0], u[t][1]);
        *reinterpret_cast<float2*>(wp + 2) = make_float2(u[t][2], u[t][3]);
        *reinterpret_cast<float2*>(wp + 4) = make_float2(u[t][4], u[t][5]);
        *reinterpret_cast<float2*>(wp + 6) = make_float2(u[t][6], u[t][7]);
        // same-wave DS ops are in-order; compiler inserts lgkmcnt before reads
        #pragma unroll
        for (int i = 0; i < 4; i++) {
            // 16 distinct rows/read (4-lane broadcast groups) = 64 cells/instr
            const float* up = &tile[wv][t & 1][js + 16 * i][0];
            float2 u0 = *reinterpret_cast<const float2*>(up + 0);
            float2 u1 = *reinterpret_cast<const float2*>(up + 2);
            float2 u2 = *reinterpret_cast<const float2*>(up + 4);
            float2 u3 = *reinterpret_cast<const float2*>(up + 6);
            #pragma unroll
            for (int k = 0; k < 4; k++) {
                float2 d = pk_fma(q01[k], u0, pk_fma(q23[k], u1, pk_fma(q45[k], u2,
                           make_float2(q67[k].x * u3.x, q67[k].y * u3.y))));
                float e = __builtin_amdgcn_exp2f(d.x + d.y);
                l[k] += e;
                float2 ev = make_float2(e, e);
                a01[k] = pk_fma(ev, u0, a01[k]); a23[k] = pk_fma(ev, u1, a23[k]);
                a45[k] = pk_fma(ev, u2, a45[k]); a67[k] = pk_fma(ev, u3, a67[k]);
            }
        }
    }

    // ---- in-wave butterfly over the 16 j-slices (lane bits 2..5) ----
    #pragma unroll
    for (int m = 4; m <= 32; m <<= 1) {
        #pragma unroll
        for (int k = 0; k < 4; k++) {
            a01[k].x += __shfl_xor(a01[k].x, m); a01[k].y += __shfl_xor(a01[k].y, m);
            a23[k].x += __shfl_xor(a23[k].x, m); a23[k].y += __shfl_xor(a23[k].y, m);
            a45[k].x += __shfl_xor(a45[k].x, m); a45[k].y += __shfl_xor(a45[k].y, m);
            a67[k].x += __shfl_xor(a67[k].x, m); a67[k].y += __shfl_xor(a67[k].y, m);
            l[k]     += __shfl_xor(l[k], m);
        }
    }
    if (js == 0) {                    // lanes 0..3 write rows 4g..4g+3
        #pragma unroll
        for (int k = 0; k < 4; k++) {
            float inv = INV_SQRT_ALPHA / l[k];
            float* cp = &ctxL[4 * g + k][h * 8];
            *reinterpret_cast<float2*>(cp + 0) = make_float2(a01[k].x * inv, a01[k].y * inv);
            *reinterpret_cast<float2*>(cp + 2) = make_float2(a23[k].x * inv, a23[k].y * inv);
            *reinterpret_cast<float2*>(cp + 4) = make_float2(a45[k].x * inv, a45[k].y * inv);
            *reinterpret_cast<float2*>(cp + 6) = make_float2(a67[k].x * inv, a67[k].y * inv);
        }
    }
    __syncthreads();                  // the ONE barrier: ctxL complete

    // ---- proj: wave wv does rows {wv, wv+8}; lane = e; Wo row in regs ----
    {
        const int e = lane;
        const float4* wp = reinterpret_cast<const float4*>(Wo + e * 64);
        float a0 = bo[e], a1 = a0;
        const int r0 = wv, r1 = wv + 8;
        #pragma unroll 4
        for (int k4 = 0; k4 < 16; k4++) {
            float4 w  = wp[k4];       // 16 KB Wo: L1/L2-hot after first block
            float4 c0 = *reinterpret_cast<const float4*>(&ctxL[r0][k4 * 4]); // bcast
            float4 c1 = *reinterpret_cast<const float4*>(&ctxL[r1][k4 * 4]);
            a0 += c0.x*w.x + c0.y*w.y + c0.z*w.z + c0.w*w.w;
            a1 += c1.x*w.x + c1.y*w.y + c1.z*w.z + c1.w*w.w;
        }
        out[(size_t)(b * 512 + chunk * 16 + r0) * 64 + e] = a0;
        out[(size_t)(b * 512 + chunk * 16 + r1) * 64 + e] = a1;
    }
}

extern "C" void kernel_launch(void* const* d_in, const int* in_sizes, int n_in,
                              void* d_out, int out_size, void* d_ws, size_t ws_size,
                              hipStream_t stream) {
    const float* x     = (const float*)d_in[0];  // [8,512,64]
    const float* theta = (const float*)d_in[1];  // [8]
    const float* Wo    = (const float*)d_in[2];  // [64,64]
    const float* bo    = (const float*)d_in[3];  // [64]
    float* out = (float*)d_out;                  // [8,512,64]

    fused_heads_kernel<<<dim3(8, 32), 512, 0, stream>>>(x, theta, Wo, bo, out);
}

// Round 9
// 76.158 us; speedup vs baseline: 1.6670x; 1.6670x over previous
//
#include <hip/hip_runtime.h>

// alpha = log2(e)/sqrt(8); Q pre-scaled by sqrt(alpha) so score = exp2(q'.q')
#define SQRT_ALPHA     0.71419163f
#define INV_SQRT_ALPHA 1.40018452f

__device__ __forceinline__ float2 pk_fma(float2 a, float2 b, float2 c) {
    return make_float2(fmaf(a.x, b.x, c.x), fmaf(a.y, b.y, c.y));
}

// analytic circuit: exp[0]=prod_{1..7}cos(x_w+th_w); exp[k]=prod_{0..k}cos(...)
__device__ __forceinline__ void qprod(float4 xa, float4 xb, const float* th,
                                      float* q) {
    float c[8];
    c[0] = __cosf(xa.x + th[0]); c[1] = __cosf(xa.y + th[1]);
    c[2] = __cosf(xa.z + th[2]); c[3] = __cosf(xa.w + th[3]);
    c[4] = __cosf(xb.x + th[4]); c[5] = __cosf(xb.y + th[5]);
    c[6] = __cosf(xb.z + th[6]); c[7] = __cosf(xb.w + th[7]);
    float pre = c[0];
    #pragma unroll
    for (int k = 1; k < 8; k++) { pre *= c[k]; q[k] = pre * SQRT_ALPHA; }
    float suf = 1.f;
    #pragma unroll
    for (int w = 7; w >= 1; w--) suf *= c[w];
    q[0] = suf * SQRT_ALPHA;
}

// ONE dispatch. grid (8 b, 32 chunks of 16 tokens), block 512 = 8 waves;
// wave wv = head wv. K processed in 8 double-buffered 64-row tiles:
// staging partition (row=tid>>3, h=tid&7) gives perfectly coalesced global
// reads (consecutive lanes -> consecutive 32B); products built in registers,
// one LDS store (pitch 66 -> conflict-free j-loop reads). Tile t+1 loads
// issue before j-loop t (latency hidden). 8 barriers. No ws / atomics /
// cross-block sync. No max-sub in softmax: |score'| <= 8*alpha = 4.08.
__global__ __launch_bounds__(512) void fused_kernel(
    const float* __restrict__ x,      // fp32 [8,512,64]
    const float* __restrict__ theta,  // fp32 [8]
    const float* __restrict__ Wo,     // fp32 [64][64]
    const float* __restrict__ bo,     // fp32 [64]
    float* __restrict__ out)          // fp32 [4096][64]
{
    __shared__ float Kt[2][64][66];   // 33.8 KB K'-tile dbuf
    __shared__ float Qp[16][66];      // 4.2 KB this chunk's Q' (all heads)
    __shared__ float ctxL[16][68];    // 4.4 KB ctx rows (16B-aligned pitch)

    const int b     = blockIdx.x;     // 0..7 (-> XCD b under %8 round-robin)
    const int chunk = blockIdx.y;     // 0..31 -> tokens [16*chunk, +16)
    const int tid  = threadIdx.x;
    const int lane = tid & 63;
    const int wv   = tid >> 6;        // 0..7 == head
    const int h    = wv;

    float th[8];
    #pragma unroll
    for (int w = 0; w < 8; w++) th[w] = theta[w];

    const float* xbase = x + (size_t)b * 512 * 64;
    const int r_  = tid >> 3;         // staging row 0..63
    const int hh_ = tid & 7;          // staging head

    // ---- Q' for this chunk: threads 0..127, coalesced 32B/lane ----
    if (tid < 128) {
        const int qr = tid >> 3, qh = tid & 7;
        const float* xp = xbase + (size_t)(chunk * 16 + qr) * 64 + qh * 8;
        float4 xa = *reinterpret_cast<const float4*>(xp);
        float4 xb = *reinterpret_cast<const float4*>(xp + 4);
        float q[8]; qprod(xa, xb, th, q);
        float* qd = &Qp[qr][qh * 8];
        *reinterpret_cast<float2*>(qd + 0) = make_float2(q[0], q[1]);
        *reinterpret_cast<float2*>(qd + 2) = make_float2(q[2], q[3]);
        *reinterpret_cast<float2*>(qd + 4) = make_float2(q[4], q[5]);
        *reinterpret_cast<float2*>(qd + 6) = make_float2(q[6], q[7]);
    }
    // ---- K' tile 0: all 512 threads, coalesced ----
    {
        const float* xp = xbase + (size_t)r_ * 64 + hh_ * 8;
        float4 xa = *reinterpret_cast<const float4*>(xp);
        float4 xb = *reinterpret_cast<const float4*>(xp + 4);
        float q[8]; qprod(xa, xb, th, q);
        float* kd = &Kt[0][r_][hh_ * 8];
        *reinterpret_cast<float2*>(kd + 0) = make_float2(q[0], q[1]);
        *reinterpret_cast<float2*>(kd + 2) = make_float2(q[2], q[3]);
        *reinterpret_cast<float2*>(kd + 4) = make_float2(q[4], q[5]);
        *reinterpret_cast<float2*>(kd + 6) = make_float2(q[6], q[7]);
    }
    __syncthreads();

    // ---- q-regs: lane g = lane&3 owns rows 4g..4g+3; js = lane>>2 ----
    const int g  = lane & 3;
    const int js = lane >> 2;         // 16 j-slices; j = js + 16*i per tile
    float2 q01[4], q23[4], q45[4], q67[4];
    #pragma unroll
    for (int k = 0; k < 4; k++) {
        const float* qp = &Qp[4 * g + k][h * 8];
        q01[k] = *reinterpret_cast<const float2*>(qp + 0);
        q23[k] = *reinterpret_cast<const float2*>(qp + 2);
        q45[k] = *reinterpret_cast<const float2*>(qp + 4);
        q67[k] = *reinterpret_cast<const float2*>(qp + 6);
    }
    float2 a01[4], a23[4], a45[4], a67[4];
    float l[4];
    #pragma unroll
    for (int k = 0; k < 4; k++) {
        a01[k] = make_float2(0.f, 0.f); a23[k] = a01[k];
        a45[k] = a01[k]; a67[k] = a01[k]; l[k] = 0.f;
    }

    // ---- K loop: 8 tiles x 64 j, double-buffered ----
    for (int t = 0; t < 8; t++) {
        float4 nxa, nxb;
        if (t < 7) {                  // issue next tile's loads (coalesced)
            const float* xp = xbase + (size_t)((t + 1) * 64 + r_) * 64 + hh_ * 8;
            nxa = *reinterpret_cast<const float4*>(xp);
            nxb = *reinterpret_cast<const float4*>(xp + 4);
        }
        const float* base = &Kt[t & 1][0][h * 8];
        #pragma unroll
        for (int i = 0; i < 4; i++) {
            // 16 distinct rows (4-lane broadcast groups), conflict-free
            const float* up = base + (js + 16 * i) * 66;
            float2 u0 = *reinterpret_cast<const float2*>(up + 0);
            float2 u1 = *reinterpret_cast<const float2*>(up + 2);
            float2 u2 = *reinterpret_cast<const float2*>(up + 4);
            float2 u3 = *reinterpret_cast<const float2*>(up + 6);
            #pragma unroll
            for (int k = 0; k < 4; k++) {
                float2 d = pk_fma(q01[k], u0, pk_fma(q23[k], u1, pk_fma(q45[k], u2,
                           make_float2(q67[k].x * u3.x, q67[k].y * u3.y))));
                float e = __builtin_amdgcn_exp2f(d.x + d.y);
                l[k] += e;
                float2 ev = make_float2(e, e);
                a01[k] = pk_fma(ev, u0, a01[k]); a23[k] = pk_fma(ev, u1, a23[k]);
                a45[k] = pk_fma(ev, u2, a45[k]); a67[k] = pk_fma(ev, u3, a67[k]);
            }
        }
        if (t < 7) {                  // build + store next tile
            float q[8]; qprod(nxa, nxb, th, q);
            float* kd = &Kt[(t + 1) & 1][r_][hh_ * 8];
            *reinterpret_cast<float2*>(kd + 0) = make_float2(q[0], q[1]);
            *reinterpret_cast<float2*>(kd + 2) = make_float2(q[2], q[3]);
            *reinterpret_cast<float2*>(kd + 4) = make_float2(q[4], q[5]);
            *reinterpret_cast<float2*>(kd + 6) = make_float2(q[6], q[7]);
        }
        __syncthreads();
    }

    // ---- in-wave butterfly over js (lane bits 2..5) ----
    #pragma unroll
    for (int m = 4; m <= 32; m <<= 1) {
        #pragma unroll
        for (int k = 0; k < 4; k++) {
            a01[k].x += __shfl_xor(a01[k].x, m); a01[k].y += __shfl_xor(a01[k].y, m);
            a23[k].x += __shfl_xor(a23[k].x, m); a23[k].y += __shfl_xor(a23[k].y, m);
            a45[k].x += __shfl_xor(a45[k].x, m); a45[k].y += __shfl_xor(a45[k].y, m);
            a67[k].x += __shfl_xor(a67[k].x, m); a67[k].y += __shfl_xor(a67[k].y, m);
            l[k]     += __shfl_xor(l[k], m);
        }
    }
    if (js == 0) {                    // lanes 0..3 write rows 4g..4g+3
        #pragma unroll
        for (int k = 0; k < 4; k++) {
            float inv = INV_SQRT_ALPHA / l[k];
            float* cp = &ctxL[4 * g + k][h * 8];
            *reinterpret_cast<float2*>(cp + 0) = make_float2(a01[k].x * inv, a01[k].y * inv);
            *reinterpret_cast<float2*>(cp + 2) = make_float2(a23[k].x * inv, a23[k].y * inv);
            *reinterpret_cast<float2*>(cp + 4) = make_float2(a45[k].x * inv, a45[k].y * inv);
            *reinterpret_cast<float2*>(cp + 6) = make_float2(a67[k].x * inv, a67[k].y * inv);
        }
    }
    __syncthreads();                  // ctxL complete

    // ---- proj: wave wv does rows {wv, wv+8}; lane = e (R8-proven) ----
    {
        const int e = lane;
        const float4* wp = reinterpret_cast<const float4*>(Wo + e * 64);
        float a0 = bo[e], a1 = a0;
        const int r0 = wv, r1 = wv + 8;
        #pragma unroll 4
        for (int k4 = 0; k4 < 16; k4++) {
            float4 w  = wp[k4];       // 16 KB Wo: L2-hot after first blocks
            float4 c0 = *reinterpret_cast<const float4*>(&ctxL[r0][k4 * 4]);
            float4 c1 = *reinterpret_cast<const float4*>(&ctxL[r1][k4 * 4]);
            a0 += c0.x*w.x + c0.y*w.y + c0.z*w.z + c0.w*w.w;
            a1 += c1.x*w.x + c1.y*w.y + c1.z*w.z + c1.w*w.w;
        }
        out[(size_t)(b * 512 + chunk * 16 + r0) * 64 + e] = a0;
        out[(size_t)(b * 512 + chunk * 16 + r1) * 64 + e] = a1;
    }
}

extern "C" void kernel_launch(void* const* d_in, const int* in_sizes, int n_in,
                              void* d_out, int out_size, void* d_ws, size_t ws_size,
                              hipStream_t stream) {
    const float* x     = (const float*)d_in[0];  // [8,512,64]
    const float* theta = (const float*)d_in[1];  // [8]
    const float* Wo    = (const float*)d_in[2];  // [64,64]
    const float* bo    = (const float*)d_in[3];  // [64]
    float* out = (float*)d_out;                  // [8,512,64]

    fused_kernel<<<dim3(8, 32), 512, 0, stream>>>(x, theta, Wo, bo, out);
}